// Round 3
// baseline (400.793 us; speedup 1.0000x reference)
//
#include <hip/hip_runtime.h>
#include <cmath>

// ---------------------------------------------------------------------------
// SConvNetBlock: LN1 -> SiLU -> complex-decay scan (== reference FFT conv)
//                -> *sc_lin -> +res -> LN2 -> FFN(GEMM+SiLU+GEMM) -> +res
//  * sconv: c[l] = p*c[l-1] + h[l], c[-1]=last, out = Re(c).  Chunked scan,
//    CHUNKS=64 x CLEN=32; h kept in fp16 (halves scan traffic).
//  * LN: one wave per row (16 el/lane, shuffle-only reduce), fp16 out.
//  * GEMMs fp16 MFMA 16x16x32, fp32 acc, 128x128 tile, BK=64,
//    global_load_lds w=16 staging, XOR-swizzled LDS (0 bank conflicts).
//  * x2 stored in d_out (fully written before LN2/GEMM2 read it).
// ---------------------------------------------------------------------------

#define DIMD 1024
#define FFD  4096
#define BATCH 4
#define SEQL 2048
#define MROWS (BATCH*SEQL)      // 8192
#define EPSF 1e-5f
#define CHUNKS 64
#define CLEN (SEQL/CHUNKS)      // 32

typedef __attribute__((ext_vector_type(8))) _Float16 half8;
typedef __attribute__((ext_vector_type(4))) _Float16 half4;
typedef __attribute__((ext_vector_type(4))) float    floatx4;

// ---- workspace layout (bytes) ----
#define H_OFF    0u            // h   fp16 [8192][1024]        16 MB
#define E_OFF    16777216u     // e   float2 [4][64][1024]      2 MB
#define SIN_OFF  18874368u     // sv  float2 [4][64][1024]      2 MB
#define H2_OFF   20971520u     // h2  fp16 [8192][1024]        16 MB
#define W1H_OFF  37748736u     // w1h fp16 [4096][1024]         8 MB
#define W2H_OFF  46137344u     // w2h fp16 [1024][4096]         8 MB
#define Y1_OFF   54525952u     // y1  fp16 [8192][4096]        64 MB
// total ~118 MB

__device__ __forceinline__ void load_lds16(const _Float16* g, _Float16* l) {
    __builtin_amdgcn_global_load_lds(
        (const __attribute__((address_space(1))) unsigned int*)g,
        (__attribute__((address_space(3))) unsigned int*)l,
        16, 0, 0);
}

// both weight casts in one kernel
__global__ __launch_bounds__(256)
void cast2_f32_f16(const float* __restrict__ w1, const float* __restrict__ w2,
                   _Float16* __restrict__ o1, _Float16* __restrict__ o2) {
    int i = (blockIdx.x * 256 + threadIdx.x) * 4;
    const float* src = w1;
    _Float16* dst = o1;
    if (i >= FFD * DIMD) { i -= FFD * DIMD; src = w2; dst = o2; }
    float4 v = *(const float4*)(src + i);
    half4 o;
    o.x = (_Float16)v.x; o.y = (_Float16)v.y; o.z = (_Float16)v.z; o.w = (_Float16)v.w;
    *(half4*)(dst + i) = o;
}

// one wave per row; 16 elements per lane; silu optional; fp16 out
__global__ __launch_bounds__(256)
void ln_kernel(const float* __restrict__ x, const float* __restrict__ w,
               const float* __restrict__ b, _Float16* __restrict__ oh, int do_silu) {
    const int wave = threadIdx.x >> 6;
    const int lane = threadIdx.x & 63;
    const size_t row = (size_t)blockIdx.x * 4 + wave;
    const float* xp = x + row * DIMD + lane * 16;
    float4 v[4];
    float s = 0.f, q = 0.f;
    #pragma unroll
    for (int t = 0; t < 4; ++t) {
        v[t] = *(const float4*)(xp + t * 4);
        s += (v[t].x + v[t].y) + (v[t].z + v[t].w);
        q += (v[t].x * v[t].x + v[t].y * v[t].y) + (v[t].z * v[t].z + v[t].w * v[t].w);
    }
    #pragma unroll
    for (int off = 32; off; off >>= 1) {
        s += __shfl_down(s, off, 64);
        q += __shfl_down(q, off, 64);
    }
    s = __shfl(s, 0, 64);
    q = __shfl(q, 0, 64);
    const float mu = s * (1.f / DIMD);
    const float rs = rsqrtf(q * (1.f / DIMD) - mu * mu + EPSF);
    #pragma unroll
    for (int t = 0; t < 4; ++t) {
        float4 wv = *(const float4*)(w + lane * 16 + t * 4);
        float4 bv = *(const float4*)(b + lane * 16 + t * 4);
        float o0 = (v[t].x - mu) * rs * wv.x + bv.x;
        float o1 = (v[t].y - mu) * rs * wv.y + bv.y;
        float o2 = (v[t].z - mu) * rs * wv.z + bv.z;
        float o3 = (v[t].w - mu) * rs * wv.w + bv.w;
        if (do_silu) {
            o0 = o0 / (1.f + __expf(-o0));
            o1 = o1 / (1.f + __expf(-o1));
            o2 = o2 / (1.f + __expf(-o2));
            o3 = o3 / (1.f + __expf(-o3));
        }
        half4 hv;
        hv.x = (_Float16)o0; hv.y = (_Float16)o1;
        hv.z = (_Float16)o2; hv.w = (_Float16)o3;
        *(half4*)(oh + row * DIMD + lane * 16 + t * 4) = hv;
    }
}

__device__ __forceinline__ void get_p(const float* pre, const float* pim, int d,
                                      float& pr, float& pi) {
    float re = pre[d], im = pim[d];
    float r = sqrtf(re * re + im * im);
    float t = tanhf(r) / fmaxf(r, 1e-30f);
    pr = re * t; pi = im * t;
}

// per-chunk local scan (zero init) -> end state e[b][c][d]; 4 cols/thread
__global__ __launch_bounds__(256)
void scan_partial(const _Float16* __restrict__ h, const float* __restrict__ pre,
                  const float* __restrict__ pim, float2* __restrict__ e) {
    const int d0 = threadIdx.x * 4;
    const int c = blockIdx.x;
    const int bb = blockIdx.y;
    float pr[4], pi[4], sr[4] = {}, si[4] = {};
    #pragma unroll
    for (int q = 0; q < 4; ++q) get_p(pre, pim, d0 + q, pr[q], pi[q]);
    const _Float16* hp = h + ((size_t)bb * SEQL + (size_t)c * CLEN) * DIMD + d0;
    #pragma unroll 4
    for (int j = 0; j < CLEN; ++j) {
        half4 hv = *(const half4*)(hp + (size_t)j * DIMD);
        #pragma unroll
        for (int q = 0; q < 4; ++q) {
            float nr = pr[q] * sr[q] - pi[q] * si[q] + (float)hv[q];
            float ni = pr[q] * si[q] + pi[q] * sr[q];
            sr[q] = nr; si[q] = ni;
        }
    }
    float2* ep = e + ((size_t)bb * CHUNKS + c) * DIMD + d0;
    #pragma unroll
    for (int q = 0; q < 4; ++q) ep[q] = make_float2(sr[q], si[q]);
}

// sequential combine over chunks: sv[b][c][d] = state entering chunk c
__global__ __launch_bounds__(256)
void scan_combine(const float2* __restrict__ e, const float* __restrict__ pre,
                  const float* __restrict__ pim, const float* __restrict__ lre,
                  const float* __restrict__ lim, float2* __restrict__ sv) {
    const int d0 = threadIdx.x * 4;
    const int bb = blockIdx.y;
    float pr[4], pi[4], qr[4], qi[4], sr[4], si[4];
    #pragma unroll
    for (int q = 0; q < 4; ++q) {
        get_p(pre, pim, d0 + q, pr[q], pi[q]);
        qr[q] = pr[q]; qi[q] = pi[q];
        #pragma unroll
        for (int s = 0; s < 5; ++s) {         // p^32 via 5 squarings
            float nr = qr[q] * qr[q] - qi[q] * qi[q];
            float ni = 2.f * qr[q] * qi[q];
            qr[q] = nr; qi[q] = ni;
        }
        sr[q] = lre[d0 + q]; si[q] = lim[d0 + q];
    }
    for (int c = 0; c < CHUNKS; ++c) {
        const size_t base = ((size_t)bb * CHUNKS + c) * DIMD + d0;
        #pragma unroll
        for (int q = 0; q < 4; ++q) {
            sv[base + q] = make_float2(sr[q], si[q]);
            float2 ec = e[base + q];
            float nr = qr[q] * sr[q] - qi[q] * si[q] + ec.x;
            float ni = qr[q] * si[q] + qi[q] * sr[q] + ec.y;
            sr[q] = nr; si[q] = ni;
        }
    }
}

// final scan with true incoming state; x2 = x + sc*Re(c) -> d_out
__global__ __launch_bounds__(256)
void scan_final(const _Float16* __restrict__ h, const float* __restrict__ x,
                const float* __restrict__ pre, const float* __restrict__ pim,
                const float* __restrict__ sc, const float2* __restrict__ sv,
                float* __restrict__ x2) {
    const int d0 = threadIdx.x * 4;
    const int c = blockIdx.x;
    const int bb = blockIdx.y;
    float pr[4], pi[4], sr[4], si[4];
    #pragma unroll
    for (int q = 0; q < 4; ++q) {
        get_p(pre, pim, d0 + q, pr[q], pi[q]);
        float2 s0 = sv[((size_t)bb * CHUNKS + c) * DIMD + d0 + q];
        sr[q] = s0.x; si[q] = s0.y;
    }
    float4 scv = *(const float4*)(sc + d0);
    const size_t base = ((size_t)bb * SEQL + (size_t)c * CLEN) * DIMD + d0;
    #pragma unroll 4
    for (int j = 0; j < CLEN; ++j) {
        half4 hv = *(const half4*)(h + base + (size_t)j * DIMD);
        float4 xv = *(const float4*)(x + base + (size_t)j * DIMD);
        float4 ov;
        #pragma unroll
        for (int q = 0; q < 4; ++q) {
            float nr = pr[q] * sr[q] - pi[q] * si[q] + (float)hv[q];
            float ni = pr[q] * si[q] + pi[q] * sr[q];
            sr[q] = nr; si[q] = ni;
        }
        ov.x = xv.x + scv.x * sr[0];
        ov.y = xv.y + scv.y * sr[1];
        ov.z = xv.z + scv.z * sr[2];
        ov.w = xv.w + scv.w * sr[3];
        *(float4*)(x2 + base + (size_t)j * DIMD) = ov;
    }
}

// ---- GEMM: C[M][N] = A[M][K] * W[N][K]^T, fp16 in, fp32 acc ----
#define BM 128
#define BN 128
#define BK 64

__global__ __launch_bounds__(256)
void gemm_bt(const _Float16* __restrict__ A, const _Float16* __restrict__ W,
             const float* __restrict__ bias, _Float16* __restrict__ out_h,
             const float* resid, float* out_f, int N, int K, int epi) {
    __shared__ _Float16 As[BM * BK];
    __shared__ _Float16 Bs[BN * BK];
    const int tid  = threadIdx.x;
    const int lane = tid & 63;
    const int wave = tid >> 6;
    const int wm = (wave >> 1) * 64;
    const int wn = (wave & 1) * 64;
    const size_t m0 = (size_t)blockIdx.y * BM;
    const size_t n0 = (size_t)blockIdx.x * BN;
    const int fr = lane & 15;
    const int quad = lane >> 4;

    // staging: wave handles rows [wave*32, wave*32+32); each issue = 8 rows.
    // LDS slot (row, cc) <- global chunk cc ^ (row&7); row&7 == lane>>3.
    const int srow = wave * 32 + (lane >> 3);
    const int ccp  = ((lane & 7) ^ (lane >> 3)) * 8;   // swizzled global chunk (halfs)
    const _Float16* ag = A + (m0 + srow) * (size_t)K + ccp;
    const _Float16* wg = W + (n0 + srow) * (size_t)K + ccp;
    _Float16* asl = &As[(wave * 32) * BK];
    _Float16* bsl = &Bs[(wave * 32) * BK];

    floatx4 acc[4][4] = {};

    for (int k0 = 0; k0 < K; k0 += BK) {
        #pragma unroll
        for (int t = 0; t < 4; ++t) {
            load_lds16(ag + k0 + (size_t)(t * 8) * K, asl + t * 8 * BK);
            load_lds16(wg + k0 + (size_t)(t * 8) * K, bsl + t * 8 * BK);
        }
        __syncthreads();
        #pragma unroll
        for (int kk = 0; kk < BK; kk += 32) {
            half8 af[4], bf[4];
            #pragma unroll
            for (int i = 0; i < 4; ++i) {
                const int slot = (((kk >> 3) + quad) ^ (fr & 7)) * 8;
                af[i] = *(const half8*)(&As[(wm + i * 16 + fr) * BK + slot]);
                bf[i] = *(const half8*)(&Bs[(wn + i * 16 + fr) * BK + slot]);
            }
            #pragma unroll
            for (int i = 0; i < 4; ++i)
                #pragma unroll
                for (int j = 0; j < 4; ++j)
                    acc[i][j] = __builtin_amdgcn_mfma_f32_16x16x32_f16(
                        af[i], bf[j], acc[i][j], 0, 0, 0);
        }
        __syncthreads();
    }

    #pragma unroll
    for (int i = 0; i < 4; ++i) {
        #pragma unroll
        for (int j = 0; j < 4; ++j) {
            #pragma unroll
            for (int r = 0; r < 4; ++r) {
                const size_t gm = m0 + wm + i * 16 + quad * 4 + r;
                const size_t gn = n0 + wn + j * 16 + fr;
                float v = acc[i][j][r] + bias[gn];
                if (epi == 1) {
                    float sl = v / (1.f + __expf(-v));
                    out_h[gm * N + gn] = (_Float16)sl;
                } else {
                    out_f[gm * N + gn] = v + resid[gm * N + gn];
                }
            }
        }
    }
}

extern "C" void kernel_launch(void* const* d_in, const int* in_sizes, int n_in,
                              void* d_out, int out_size, void* d_ws, size_t ws_size,
                              hipStream_t stream) {
    const float* x    = (const float*)d_in[0];
    const float* ln1w = (const float*)d_in[1];
    const float* ln1b = (const float*)d_in[2];
    const float* ln2w = (const float*)d_in[3];
    const float* ln2b = (const float*)d_in[4];
    const float* sc   = (const float*)d_in[5];
    const float* pre  = (const float*)d_in[6];
    const float* pim  = (const float*)d_in[7];
    const float* lre  = (const float*)d_in[8];
    const float* lim  = (const float*)d_in[9];
    const float* w1   = (const float*)d_in[10];
    const float* b1   = (const float*)d_in[11];
    const float* w2   = (const float*)d_in[12];
    const float* b2   = (const float*)d_in[13];

    char* ws = (char*)d_ws;
    _Float16*   h   = (_Float16*)(ws + H_OFF);
    float2*     e   = (float2*)(ws + E_OFF);
    float2*     sv  = (float2*)(ws + SIN_OFF);
    _Float16*   h2  = (_Float16*)(ws + H2_OFF);
    _Float16*   w1h = (_Float16*)(ws + W1H_OFF);
    _Float16*   w2h = (_Float16*)(ws + W2H_OFF);
    _Float16*   y1  = (_Float16*)(ws + Y1_OFF);
    float*      x2  = (float*)d_out;
    float*      outp = (float*)d_out;

    cast2_f32_f16<<<dim3(2 * FFD * DIMD / 1024), 256, 0, stream>>>(w1, w2, w1h, w2h);
    ln_kernel<<<dim3(MROWS / 4), 256, 0, stream>>>(x, ln1w, ln1b, h, 1);
    scan_partial<<<dim3(CHUNKS, BATCH), 256, 0, stream>>>(h, pre, pim, e);
    scan_combine<<<dim3(1, BATCH), 256, 0, stream>>>(e, pre, pim, lre, lim, sv);
    scan_final<<<dim3(CHUNKS, BATCH), 256, 0, stream>>>(h, x, pre, pim, sc, sv, x2);
    ln_kernel<<<dim3(MROWS / 4), 256, 0, stream>>>(x2, ln2w, ln2b, h2, 0);
    gemm_bt<<<dim3(FFD / BN, MROWS / BM), 256, 0, stream>>>(
        h2, w1h, b1, y1, nullptr, nullptr, FFD, DIMD, 1);
    gemm_bt<<<dim3(DIMD / BN, MROWS / BM), 256, 0, stream>>>(
        y1, w2h, b2, nullptr, x2, outp, DIMD, FFD, 2);
}

// Round 4
// 395.719 us; speedup vs baseline: 1.0128x; 1.0128x over previous
//
#include <hip/hip_runtime.h>
#include <cmath>

// ---------------------------------------------------------------------------
// SConvNetBlock: LN1 -> SiLU -> complex-decay scan (== reference FFT conv)
//                -> *sc_lin -> +res -> LN2 -> FFN(GEMM+SiLU+GEMM) -> +res
//  * Fused elementwise chain: scan blocks span the full D=1024 row, so LN
//    reductions run inside the scan kernels (no h buffer, no LN kernels):
//      phase1: x -> LN1+SiLU (in-block reduce) -> local chunk scan -> e
//      combine: e -> true chunk-entry states sv (1 col/thread, 16 blocks)
//      phase2: x -> LN1+SiLU replay -> scan -> x2 = x + sc*Re(c) (write)
//              -> fused LN2 (second in-block reduce) -> h2 fp16 (write)
//    LN1 is recomputed identically in phase1/phase2 (deterministic).
//  * GEMMs fp16 MFMA 16x16x32, fp32 acc, 128x128 tile, BK=64,
//    global_load_lds w=16 staging, XOR-swizzled LDS (0 bank conflicts).
//  * x2 stored in d_out (fully written before GEMM2 reads it as residual).
// ---------------------------------------------------------------------------

#define DIMD 1024
#define FFD  4096
#define BATCH 4
#define SEQL 2048
#define MROWS (BATCH*SEQL)      // 8192
#define EPSF 1e-5f
#define CHUNKS 128
#define CLEN (SEQL/CHUNKS)      // 16

typedef __attribute__((ext_vector_type(8))) _Float16 half8;
typedef __attribute__((ext_vector_type(4))) _Float16 half4;
typedef __attribute__((ext_vector_type(4))) float    floatx4;

// ---- workspace layout (bytes) ----
#define E_OFF    0u            // e   float2 [4][128][1024]     4 MB
#define SV_OFF   4194304u      // sv  float2 [4][128][1024]     4 MB
#define H2_OFF   8388608u      // h2  fp16 [8192][1024]        16 MB
#define W1H_OFF  25165824u     // w1h fp16 [4096][1024]         8 MB
#define W2H_OFF  33554432u     // w2h fp16 [1024][4096]         8 MB
#define Y1_OFF   41943040u     // y1  fp16 [8192][4096]        64 MB
// total ~108 MB

__device__ __forceinline__ void load_lds16(const _Float16* g, _Float16* l) {
    __builtin_amdgcn_global_load_lds(
        (const __attribute__((address_space(1))) unsigned int*)g,
        (__attribute__((address_space(3))) unsigned int*)l,
        16, 0, 0);
}

__device__ __forceinline__ void wave_reduce2(float& s, float& q) {
    #pragma unroll
    for (int off = 32; off; off >>= 1) {
        s += __shfl_down(s, off, 64);
        q += __shfl_down(q, off, 64);
    }
}

__device__ __forceinline__ void get_p(const float* pre, const float* pim, int d,
                                      float& pr, float& pi) {
    float re = pre[d], im = pim[d];
    float r = sqrtf(re * re + im * im);
    float t = tanhf(r) / fmaxf(r, 1e-30f);
    pr = re * t; pi = im * t;
}

// both weight casts in one kernel
__global__ __launch_bounds__(256)
void cast2_f32_f16(const float* __restrict__ w1, const float* __restrict__ w2,
                   _Float16* __restrict__ o1, _Float16* __restrict__ o2) {
    int i = (blockIdx.x * 256 + threadIdx.x) * 4;
    const float* src = w1;
    _Float16* dst = o1;
    if (i >= FFD * DIMD) { i -= FFD * DIMD; src = w2; dst = o2; }
    float4 v = *(const float4*)(src + i);
    half4 o;
    o.x = (_Float16)v.x; o.y = (_Float16)v.y; o.z = (_Float16)v.z; o.w = (_Float16)v.w;
    *(half4*)(dst + i) = o;
}

// phase1: x -> LN1+SiLU (block reduce) -> local chunk scan (zero init) -> e
__global__ __launch_bounds__(256)
void scan_phase1(const float* __restrict__ x, const float* __restrict__ lw,
                 const float* __restrict__ lb, const float* __restrict__ pre,
                 const float* __restrict__ pim, float2* __restrict__ e) {
    const int tid = threadIdx.x;
    const int d0 = tid * 4;
    const int c = blockIdx.x, bb = blockIdx.y;
    const int lane = tid & 63, wave = tid >> 6;
    __shared__ float2 red[2][4];

    float pr[4], pi[4], sr[4] = {}, si[4] = {};
    #pragma unroll
    for (int q = 0; q < 4; ++q) get_p(pre, pim, d0 + q, pr[q], pi[q]);
    const float4 wv = *(const float4*)(lw + d0);
    const float4 bv = *(const float4*)(lb + d0);
    const size_t rowbase = ((size_t)bb * SEQL + (size_t)c * CLEN) * DIMD;

    for (int j = 0; j < CLEN; ++j) {
        float4 v = *(const float4*)(x + rowbase + (size_t)j * DIMD + d0);
        float s = (v.x + v.y) + (v.z + v.w);
        float q2 = (v.x * v.x + v.y * v.y) + (v.z * v.z + v.w * v.w);
        wave_reduce2(s, q2);
        if (lane == 0) red[j & 1][wave] = make_float2(s, q2);
        __syncthreads();
        float2 r0 = red[j & 1][0], r1 = red[j & 1][1];
        float2 r2 = red[j & 1][2], r3 = red[j & 1][3];
        s = (r0.x + r1.x) + (r2.x + r3.x);
        q2 = (r0.y + r1.y) + (r2.y + r3.y);
        const float mu = s * (1.f / DIMD);
        const float rs = rsqrtf(q2 * (1.f / DIMD) - mu * mu + EPSF);
        float o[4] = {
            (v.x - mu) * rs * wv.x + bv.x, (v.y - mu) * rs * wv.y + bv.y,
            (v.z - mu) * rs * wv.z + bv.z, (v.w - mu) * rs * wv.w + bv.w };
        #pragma unroll
        for (int q = 0; q < 4; ++q) {
            float hv = o[q] / (1.f + __expf(-o[q]));
            float nr = pr[q] * sr[q] - pi[q] * si[q] + hv;
            float ni = pr[q] * si[q] + pi[q] * sr[q];
            sr[q] = nr; si[q] = ni;
        }
    }
    float2* ep = e + ((size_t)bb * CHUNKS + c) * DIMD + d0;
    #pragma unroll
    for (int q = 0; q < 4; ++q) ep[q] = make_float2(sr[q], si[q]);
}

// sequential combine over chunks: sv[b][c][d] = state entering chunk c
__global__ __launch_bounds__(256)
void scan_combine(const float2* __restrict__ e, const float* __restrict__ pre,
                  const float* __restrict__ pim, const float* __restrict__ lre,
                  const float* __restrict__ lim, float2* __restrict__ sv) {
    const int d = blockIdx.x * 256 + threadIdx.x;
    const int bb = blockIdx.y;
    float pr, pi; get_p(pre, pim, d, pr, pi);
    float qr = pr, qi = pi;                 // p^CLEN, CLEN=16 -> 4 squarings
    #pragma unroll
    for (int s = 0; s < 4; ++s) {
        float nr = qr * qr - qi * qi;
        float ni = 2.f * qr * qi;
        qr = nr; qi = ni;
    }
    float sr = lre[d], si = lim[d];
    #pragma unroll 4
    for (int c = 0; c < CHUNKS; ++c) {
        const size_t idx = ((size_t)bb * CHUNKS + c) * DIMD + d;
        sv[idx] = make_float2(sr, si);
        float2 ec = e[idx];
        float nr = qr * sr - qi * si + ec.x;
        float ni = qr * si + qi * sr + ec.y;
        sr = nr; si = ni;
    }
}

// phase2: x -> LN1+SiLU replay -> scan (true state) -> x2 write
//         -> fused LN2 (second block reduce) -> h2 fp16 write
__global__ __launch_bounds__(256)
void scan_phase2(const float* __restrict__ x, const float* __restrict__ l1w,
                 const float* __restrict__ l1b, const float* __restrict__ l2w,
                 const float* __restrict__ l2b, const float* __restrict__ pre,
                 const float* __restrict__ pim, const float* __restrict__ sc,
                 const float2* __restrict__ sv, float* __restrict__ x2,
                 _Float16* __restrict__ h2) {
    const int tid = threadIdx.x;
    const int d0 = tid * 4;
    const int c = blockIdx.x, bb = blockIdx.y;
    const int lane = tid & 63, wave = tid >> 6;
    __shared__ float2 redA[2][4];
    __shared__ float2 redB[2][4];

    float pr[4], pi[4], sr[4], si[4];
    #pragma unroll
    for (int q = 0; q < 4; ++q) {
        get_p(pre, pim, d0 + q, pr[q], pi[q]);
        float2 s0 = sv[((size_t)bb * CHUNKS + c) * DIMD + d0 + q];
        sr[q] = s0.x; si[q] = s0.y;
    }
    const float4 w1v = *(const float4*)(l1w + d0);
    const float4 b1v = *(const float4*)(l1b + d0);
    const float4 w2v = *(const float4*)(l2w + d0);
    const float4 b2v = *(const float4*)(l2b + d0);
    const float4 scv = *(const float4*)(sc + d0);
    const size_t rowbase = ((size_t)bb * SEQL + (size_t)c * CLEN) * DIMD;

    for (int j = 0; j < CLEN; ++j) {
        float4 v = *(const float4*)(x + rowbase + (size_t)j * DIMD + d0);
        float s = (v.x + v.y) + (v.z + v.w);
        float q2 = (v.x * v.x + v.y * v.y) + (v.z * v.z + v.w * v.w);
        wave_reduce2(s, q2);
        if (lane == 0) redA[j & 1][wave] = make_float2(s, q2);
        __syncthreads();
        {
            float2 r0 = redA[j & 1][0], r1 = redA[j & 1][1];
            float2 r2 = redA[j & 1][2], r3 = redA[j & 1][3];
            s = (r0.x + r1.x) + (r2.x + r3.x);
            q2 = (r0.y + r1.y) + (r2.y + r3.y);
        }
        const float mu = s * (1.f / DIMD);
        const float rs = rsqrtf(q2 * (1.f / DIMD) - mu * mu + EPSF);
        float o[4] = {
            (v.x - mu) * rs * w1v.x + b1v.x, (v.y - mu) * rs * w1v.y + b1v.y,
            (v.z - mu) * rs * w1v.z + b1v.z, (v.w - mu) * rs * w1v.w + b1v.w };
        #pragma unroll
        for (int q = 0; q < 4; ++q) {
            float hv = o[q] / (1.f + __expf(-o[q]));
            float nr = pr[q] * sr[q] - pi[q] * si[q] + hv;
            float ni = pr[q] * si[q] + pi[q] * sr[q];
            sr[q] = nr; si[q] = ni;
        }
        float4 xv;
        xv.x = v.x + scv.x * sr[0];
        xv.y = v.y + scv.y * sr[1];
        xv.z = v.z + scv.z * sr[2];
        xv.w = v.w + scv.w * sr[3];
        *(float4*)(x2 + rowbase + (size_t)j * DIMD + d0) = xv;
        // fused LN2
        float s2 = (xv.x + xv.y) + (xv.z + xv.w);
        float q3 = (xv.x * xv.x + xv.y * xv.y) + (xv.z * xv.z + xv.w * xv.w);
        wave_reduce2(s2, q3);
        if (lane == 0) redB[j & 1][wave] = make_float2(s2, q3);
        __syncthreads();
        {
            float2 r0 = redB[j & 1][0], r1 = redB[j & 1][1];
            float2 r2 = redB[j & 1][2], r3 = redB[j & 1][3];
            s2 = (r0.x + r1.x) + (r2.x + r3.x);
            q3 = (r0.y + r1.y) + (r2.y + r3.y);
        }
        const float mu2 = s2 * (1.f / DIMD);
        const float rs2 = rsqrtf(q3 * (1.f / DIMD) - mu2 * mu2 + EPSF);
        half4 hh;
        hh.x = (_Float16)((xv.x - mu2) * rs2 * w2v.x + b2v.x);
        hh.y = (_Float16)((xv.y - mu2) * rs2 * w2v.y + b2v.y);
        hh.z = (_Float16)((xv.z - mu2) * rs2 * w2v.z + b2v.z);
        hh.w = (_Float16)((xv.w - mu2) * rs2 * w2v.w + b2v.w);
        *(half4*)(h2 + rowbase + (size_t)j * DIMD + d0) = hh;
    }
}

// ---- GEMM: C[M][N] = A[M][K] * W[N][K]^T, fp16 in, fp32 acc ----
#define BM 128
#define BN 128
#define BK 64

__global__ __launch_bounds__(256)
void gemm_bt(const _Float16* __restrict__ A, const _Float16* __restrict__ W,
             const float* __restrict__ bias, _Float16* __restrict__ out_h,
             const float* resid, float* out_f, int N, int K, int epi) {
    __shared__ _Float16 As[BM * BK];
    __shared__ _Float16 Bs[BN * BK];
    const int tid  = threadIdx.x;
    const int lane = tid & 63;
    const int wave = tid >> 6;
    const int wm = (wave >> 1) * 64;
    const int wn = (wave & 1) * 64;
    const size_t m0 = (size_t)blockIdx.y * BM;
    const size_t n0 = (size_t)blockIdx.x * BN;
    const int fr = lane & 15;
    const int quad = lane >> 4;

    // staging: wave handles rows [wave*32, wave*32+32); each issue = 8 rows.
    // LDS slot (row, cc) <- global chunk cc ^ (row&7); row&7 == lane>>3.
    const int srow = wave * 32 + (lane >> 3);
    const int ccp  = ((lane & 7) ^ (lane >> 3)) * 8;   // swizzled global chunk (halfs)
    const _Float16* ag = A + (m0 + srow) * (size_t)K + ccp;
    const _Float16* wg = W + (n0 + srow) * (size_t)K + ccp;
    _Float16* asl = &As[(wave * 32) * BK];
    _Float16* bsl = &Bs[(wave * 32) * BK];

    floatx4 acc[4][4] = {};

    for (int k0 = 0; k0 < K; k0 += BK) {
        #pragma unroll
        for (int t = 0; t < 4; ++t) {
            load_lds16(ag + k0 + (size_t)(t * 8) * K, asl + t * 8 * BK);
            load_lds16(wg + k0 + (size_t)(t * 8) * K, bsl + t * 8 * BK);
        }
        __syncthreads();
        #pragma unroll
        for (int kk = 0; kk < BK; kk += 32) {
            half8 af[4], bf[4];
            #pragma unroll
            for (int i = 0; i < 4; ++i) {
                const int slot = (((kk >> 3) + quad) ^ (fr & 7)) * 8;
                af[i] = *(const half8*)(&As[(wm + i * 16 + fr) * BK + slot]);
                bf[i] = *(const half8*)(&Bs[(wn + i * 16 + fr) * BK + slot]);
            }
            #pragma unroll
            for (int i = 0; i < 4; ++i)
                #pragma unroll
                for (int j = 0; j < 4; ++j)
                    acc[i][j] = __builtin_amdgcn_mfma_f32_16x16x32_f16(
                        af[i], bf[j], acc[i][j], 0, 0, 0);
        }
        __syncthreads();
    }

    #pragma unroll
    for (int i = 0; i < 4; ++i) {
        #pragma unroll
        for (int j = 0; j < 4; ++j) {
            #pragma unroll
            for (int r = 0; r < 4; ++r) {
                const size_t gm = m0 + wm + i * 16 + quad * 4 + r;
                const size_t gn = n0 + wn + j * 16 + fr;
                float v = acc[i][j][r] + bias[gn];
                if (epi == 1) {
                    float sl = v / (1.f + __expf(-v));
                    out_h[gm * N + gn] = (_Float16)sl;
                } else {
                    out_f[gm * N + gn] = v + resid[gm * N + gn];
                }
            }
        }
    }
}

extern "C" void kernel_launch(void* const* d_in, const int* in_sizes, int n_in,
                              void* d_out, int out_size, void* d_ws, size_t ws_size,
                              hipStream_t stream) {
    const float* x    = (const float*)d_in[0];
    const float* ln1w = (const float*)d_in[1];
    const float* ln1b = (const float*)d_in[2];
    const float* ln2w = (const float*)d_in[3];
    const float* ln2b = (const float*)d_in[4];
    const float* sc   = (const float*)d_in[5];
    const float* pre  = (const float*)d_in[6];
    const float* pim  = (const float*)d_in[7];
    const float* lre  = (const float*)d_in[8];
    const float* lim  = (const float*)d_in[9];
    const float* w1   = (const float*)d_in[10];
    const float* b1   = (const float*)d_in[11];
    const float* w2   = (const float*)d_in[12];
    const float* b2   = (const float*)d_in[13];

    char* ws = (char*)d_ws;
    float2*     e   = (float2*)(ws + E_OFF);
    float2*     sv  = (float2*)(ws + SV_OFF);
    _Float16*   h2  = (_Float16*)(ws + H2_OFF);
    _Float16*   w1h = (_Float16*)(ws + W1H_OFF);
    _Float16*   w2h = (_Float16*)(ws + W2H_OFF);
    _Float16*   y1  = (_Float16*)(ws + Y1_OFF);
    float*      x2  = (float*)d_out;
    float*      outp = (float*)d_out;

    cast2_f32_f16<<<dim3(2 * FFD * DIMD / 1024), 256, 0, stream>>>(w1, w2, w1h, w2h);
    scan_phase1<<<dim3(CHUNKS, BATCH), 256, 0, stream>>>(x, ln1w, ln1b, pre, pim, e);
    scan_combine<<<dim3(DIMD / 256, BATCH), 256, 0, stream>>>(e, pre, pim, lre, lim, sv);
    scan_phase2<<<dim3(CHUNKS, BATCH), 256, 0, stream>>>(
        x, ln1w, ln1b, ln2w, ln2b, pre, pim, sc, sv, x2, h2);
    gemm_bt<<<dim3(FFD / BN, MROWS / BM), 256, 0, stream>>>(
        h2, w1h, b1, y1, nullptr, nullptr, FFD, DIMD, 1);
    gemm_bt<<<dim3(DIMD / BN, MROWS / BM), 256, 0, stream>>>(
        y1, w2h, b2, nullptr, x2, outp, DIMD, FFD, 2);
}

// Round 5
// 393.203 us; speedup vs baseline: 1.0193x; 1.0064x over previous
//
#include <hip/hip_runtime.h>
#include <cmath>

// ---------------------------------------------------------------------------
// SConvNetBlock: LN1 -> SiLU -> complex-decay scan (== reference FFT conv)
//                -> *sc_lin -> +res -> LN2 -> FFN(GEMM+SiLU+GEMM) -> +res
//  * Elementwise chain: CLEN=8 rows per block, ALL rows loaded to registers
//    up front (pipelined HBM), LN reductions batched -> ONE barrier per
//    phase-kernel pass (2 in phase2). No per-row barriers.
//      phase1: x -> LN1+SiLU -> local chunk scan -> e
//      combine: e -> chunk-entry states sv
//      phase2: x -> LN1+SiLU replay -> scan -> x2 (d_out) -> fused LN2 -> h2
//  * GEMMs fp16 MFMA 16x16x32, fp32 acc, 128x128 tile, BK=64,
//    global_load_lds w=16 staging, XOR-swizzled LDS (0 bank conflicts).
// ---------------------------------------------------------------------------

#define DIMD 1024
#define FFD  4096
#define BATCH 4
#define SEQL 2048
#define MROWS (BATCH*SEQL)      // 8192
#define EPSF 1e-5f
#define CHUNKS 256
#define CLEN (SEQL/CHUNKS)      // 8

typedef __attribute__((ext_vector_type(8))) _Float16 half8;
typedef __attribute__((ext_vector_type(4))) _Float16 half4;
typedef __attribute__((ext_vector_type(4))) float    floatx4;

// ---- workspace layout (bytes) ----
#define E_OFF    0u            // e   float2 [4][256][1024]     8 MB
#define SV_OFF   8388608u      // sv  float2 [4][256][1024]     8 MB
#define H2_OFF   16777216u     // h2  fp16 [8192][1024]        16 MB
#define W1H_OFF  33554432u     // w1h fp16 [4096][1024]         8 MB
#define W2H_OFF  41943040u     // w2h fp16 [1024][4096]         8 MB
#define Y1_OFF   50331648u     // y1  fp16 [8192][4096]        64 MB
// total ~114 MB

__device__ __forceinline__ void load_lds16(const _Float16* g, _Float16* l) {
    __builtin_amdgcn_global_load_lds(
        (const __attribute__((address_space(1))) unsigned int*)g,
        (__attribute__((address_space(3))) unsigned int*)l,
        16, 0, 0);
}

__device__ __forceinline__ void wave_reduce2(float& s, float& q) {
    #pragma unroll
    for (int off = 32; off; off >>= 1) {
        s += __shfl_down(s, off, 64);
        q += __shfl_down(q, off, 64);
    }
}

__device__ __forceinline__ void get_p(const float* pre, const float* pim, int d,
                                      float& pr, float& pi) {
    float re = pre[d], im = pim[d];
    float r = sqrtf(re * re + im * im);
    float t = tanhf(r) / fmaxf(r, 1e-30f);
    pr = re * t; pi = im * t;
}

// both weight casts in one kernel
__global__ __launch_bounds__(256)
void cast2_f32_f16(const float* __restrict__ w1, const float* __restrict__ w2,
                   _Float16* __restrict__ o1, _Float16* __restrict__ o2) {
    int i = (blockIdx.x * 256 + threadIdx.x) * 4;
    const float* src = w1;
    _Float16* dst = o1;
    if (i >= FFD * DIMD) { i -= FFD * DIMD; src = w2; dst = o2; }
    float4 v = *(const float4*)(src + i);
    half4 o;
    o.x = (_Float16)v.x; o.y = (_Float16)v.y; o.z = (_Float16)v.z; o.w = (_Float16)v.w;
    *(half4*)(dst + i) = o;
}

// phase1: x -> LN1+SiLU -> local chunk scan (zero init) -> e
__global__ __launch_bounds__(256)
void scan_phase1(const float* __restrict__ x, const float* __restrict__ lw,
                 const float* __restrict__ lb, const float* __restrict__ pre,
                 const float* __restrict__ pim, float2* __restrict__ e) {
    const int tid = threadIdx.x;
    const int d0 = tid * 4;
    const int c = blockIdx.x, bb = blockIdx.y;
    const int lane = tid & 63, wave = tid >> 6;
    __shared__ float2 red[CLEN][4];

    const size_t rowbase = ((size_t)bb * SEQL + (size_t)c * CLEN) * DIMD;
    float4 xv[CLEN];
    #pragma unroll
    for (int j = 0; j < CLEN; ++j)
        xv[j] = *(const float4*)(x + rowbase + (size_t)j * DIMD + d0);

    #pragma unroll
    for (int j = 0; j < CLEN; ++j) {
        float s = (xv[j].x + xv[j].y) + (xv[j].z + xv[j].w);
        float q = (xv[j].x * xv[j].x + xv[j].y * xv[j].y)
                + (xv[j].z * xv[j].z + xv[j].w * xv[j].w);
        wave_reduce2(s, q);
        if (lane == 0) red[j][wave] = make_float2(s, q);
    }
    __syncthreads();

    float pr[4], pi[4], sr[4] = {}, si[4] = {};
    #pragma unroll
    for (int q = 0; q < 4; ++q) get_p(pre, pim, d0 + q, pr[q], pi[q]);
    const float4 wv = *(const float4*)(lw + d0);
    const float4 bv = *(const float4*)(lb + d0);

    #pragma unroll
    for (int j = 0; j < CLEN; ++j) {
        float2 r0 = red[j][0], r1 = red[j][1], r2 = red[j][2], r3 = red[j][3];
        float s = (r0.x + r1.x) + (r2.x + r3.x);
        float q2 = (r0.y + r1.y) + (r2.y + r3.y);
        const float mu = s * (1.f / DIMD);
        const float rs = rsqrtf(q2 * (1.f / DIMD) - mu * mu + EPSF);
        float o[4] = {
            (xv[j].x - mu) * rs * wv.x + bv.x, (xv[j].y - mu) * rs * wv.y + bv.y,
            (xv[j].z - mu) * rs * wv.z + bv.z, (xv[j].w - mu) * rs * wv.w + bv.w };
        #pragma unroll
        for (int q = 0; q < 4; ++q) {
            float hv = o[q] / (1.f + __expf(-o[q]));
            float nr = pr[q] * sr[q] - pi[q] * si[q] + hv;
            float ni = pr[q] * si[q] + pi[q] * sr[q];
            sr[q] = nr; si[q] = ni;
        }
    }
    float2* ep = e + ((size_t)bb * CHUNKS + c) * DIMD + d0;
    #pragma unroll
    for (int q = 0; q < 4; ++q) ep[q] = make_float2(sr[q], si[q]);
}

// sequential combine over chunks: sv[b][c][d] = state entering chunk c
__global__ __launch_bounds__(256)
void scan_combine(const float2* __restrict__ e, const float* __restrict__ pre,
                  const float* __restrict__ pim, const float* __restrict__ lre,
                  const float* __restrict__ lim, float2* __restrict__ sv) {
    const int d = blockIdx.x * 256 + threadIdx.x;
    const int bb = blockIdx.y;
    float pr, pi; get_p(pre, pim, d, pr, pi);
    float qr = pr, qi = pi;                 // p^CLEN, CLEN=8 -> 3 squarings
    #pragma unroll
    for (int s = 0; s < 3; ++s) {
        float nr = qr * qr - qi * qi;
        float ni = 2.f * qr * qi;
        qr = nr; qi = ni;
    }
    float sr = lre[d], si = lim[d];
    #pragma unroll 8
    for (int c = 0; c < CHUNKS; ++c) {
        const size_t idx = ((size_t)bb * CHUNKS + c) * DIMD + d;
        sv[idx] = make_float2(sr, si);
        float2 ec = e[idx];
        float nr = qr * sr - qi * si + ec.x;
        float ni = qr * si + qi * sr + ec.y;
        sr = nr; si = ni;
    }
}

// phase2: x -> LN1+SiLU replay -> scan (true state) -> x2 write (registers
//         kept) -> batched LN2 (one more barrier) -> h2 fp16 write
__global__ __launch_bounds__(256)
void scan_phase2(const float* __restrict__ x, const float* __restrict__ l1w,
                 const float* __restrict__ l1b, const float* __restrict__ l2w,
                 const float* __restrict__ l2b, const float* __restrict__ pre,
                 const float* __restrict__ pim, const float* __restrict__ sc,
                 const float2* __restrict__ sv, float* __restrict__ x2,
                 _Float16* __restrict__ h2) {
    const int tid = threadIdx.x;
    const int d0 = tid * 4;
    const int c = blockIdx.x, bb = blockIdx.y;
    const int lane = tid & 63, wave = tid >> 6;
    __shared__ float2 redA[CLEN][4];
    __shared__ float2 redB[CLEN][4];

    const size_t rowbase = ((size_t)bb * SEQL + (size_t)c * CLEN) * DIMD;
    float4 xv[CLEN];
    #pragma unroll
    for (int j = 0; j < CLEN; ++j)
        xv[j] = *(const float4*)(x + rowbase + (size_t)j * DIMD + d0);

    #pragma unroll
    for (int j = 0; j < CLEN; ++j) {
        float s = (xv[j].x + xv[j].y) + (xv[j].z + xv[j].w);
        float q = (xv[j].x * xv[j].x + xv[j].y * xv[j].y)
                + (xv[j].z * xv[j].z + xv[j].w * xv[j].w);
        wave_reduce2(s, q);
        if (lane == 0) redA[j][wave] = make_float2(s, q);
    }
    __syncthreads();

    float pr[4], pi[4], sr[4], si[4];
    #pragma unroll
    for (int q = 0; q < 4; ++q) {
        get_p(pre, pim, d0 + q, pr[q], pi[q]);
        float2 s0 = sv[((size_t)bb * CHUNKS + c) * DIMD + d0 + q];
        sr[q] = s0.x; si[q] = s0.y;
    }
    const float4 w1v = *(const float4*)(l1w + d0);
    const float4 b1v = *(const float4*)(l1b + d0);
    const float4 scv = *(const float4*)(sc + d0);

    #pragma unroll
    for (int j = 0; j < CLEN; ++j) {
        float2 r0 = redA[j][0], r1 = redA[j][1], r2 = redA[j][2], r3 = redA[j][3];
        float s = (r0.x + r1.x) + (r2.x + r3.x);
        float q2 = (r0.y + r1.y) + (r2.y + r3.y);
        const float mu = s * (1.f / DIMD);
        const float rs = rsqrtf(q2 * (1.f / DIMD) - mu * mu + EPSF);
        float o[4] = {
            (xv[j].x - mu) * rs * w1v.x + b1v.x, (xv[j].y - mu) * rs * w1v.y + b1v.y,
            (xv[j].z - mu) * rs * w1v.z + b1v.z, (xv[j].w - mu) * rs * w1v.w + b1v.w };
        #pragma unroll
        for (int q = 0; q < 4; ++q) {
            float hv = o[q] / (1.f + __expf(-o[q]));
            float nr = pr[q] * sr[q] - pi[q] * si[q] + hv;
            float ni = pr[q] * si[q] + pi[q] * sr[q];
            sr[q] = nr; si[q] = ni;
        }
        xv[j].x += scv.x * sr[0];
        xv[j].y += scv.y * sr[1];
        xv[j].z += scv.z * sr[2];
        xv[j].w += scv.w * sr[3];
        *(float4*)(x2 + rowbase + (size_t)j * DIMD + d0) = xv[j];
    }

    // batched LN2 over the register-resident x2 rows
    #pragma unroll
    for (int j = 0; j < CLEN; ++j) {
        float s = (xv[j].x + xv[j].y) + (xv[j].z + xv[j].w);
        float q = (xv[j].x * xv[j].x + xv[j].y * xv[j].y)
                + (xv[j].z * xv[j].z + xv[j].w * xv[j].w);
        wave_reduce2(s, q);
        if (lane == 0) redB[j][wave] = make_float2(s, q);
    }
    __syncthreads();

    const float4 w2v = *(const float4*)(l2w + d0);
    const float4 b2v = *(const float4*)(l2b + d0);
    #pragma unroll
    for (int j = 0; j < CLEN; ++j) {
        float2 r0 = redB[j][0], r1 = redB[j][1], r2 = redB[j][2], r3 = redB[j][3];
        float s = (r0.x + r1.x) + (r2.x + r3.x);
        float q2 = (r0.y + r1.y) + (r2.y + r3.y);
        const float mu = s * (1.f / DIMD);
        const float rs = rsqrtf(q2 * (1.f / DIMD) - mu * mu + EPSF);
        half4 hh;
        hh.x = (_Float16)((xv[j].x - mu) * rs * w2v.x + b2v.x);
        hh.y = (_Float16)((xv[j].y - mu) * rs * w2v.y + b2v.y);
        hh.z = (_Float16)((xv[j].z - mu) * rs * w2v.z + b2v.z);
        hh.w = (_Float16)((xv[j].w - mu) * rs * w2v.w + b2v.w);
        *(half4*)(h2 + rowbase + (size_t)j * DIMD + d0) = hh;
    }
}

// ---- GEMM: C[M][N] = A[M][K] * W[N][K]^T, fp16 in, fp32 acc ----
#define BM 128
#define BN 128
#define BK 64

__global__ __launch_bounds__(256)
void gemm_bt(const _Float16* __restrict__ A, const _Float16* __restrict__ W,
             const float* __restrict__ bias, _Float16* __restrict__ out_h,
             const float* resid, float* out_f, int N, int K, int epi) {
    __shared__ _Float16 As[BM * BK];
    __shared__ _Float16 Bs[BN * BK];
    const int tid  = threadIdx.x;
    const int lane = tid & 63;
    const int wave = tid >> 6;
    const int wm = (wave >> 1) * 64;
    const int wn = (wave & 1) * 64;
    const size_t m0 = (size_t)blockIdx.y * BM;
    const size_t n0 = (size_t)blockIdx.x * BN;
    const int fr = lane & 15;
    const int quad = lane >> 4;

    // staging: wave handles rows [wave*32, wave*32+32); each issue = 8 rows.
    // LDS slot (row, cc) <- global chunk cc ^ (row&7); row&7 == lane>>3.
    const int srow = wave * 32 + (lane >> 3);
    const int ccp  = ((lane & 7) ^ (lane >> 3)) * 8;   // swizzled global chunk (halfs)
    const _Float16* ag = A + (m0 + srow) * (size_t)K + ccp;
    const _Float16* wg = W + (n0 + srow) * (size_t)K + ccp;
    _Float16* asl = &As[(wave * 32) * BK];
    _Float16* bsl = &Bs[(wave * 32) * BK];

    floatx4 acc[4][4] = {};

    for (int k0 = 0; k0 < K; k0 += BK) {
        #pragma unroll
        for (int t = 0; t < 4; ++t) {
            load_lds16(ag + k0 + (size_t)(t * 8) * K, asl + t * 8 * BK);
            load_lds16(wg + k0 + (size_t)(t * 8) * K, bsl + t * 8 * BK);
        }
        __syncthreads();
        #pragma unroll
        for (int kk = 0; kk < BK; kk += 32) {
            half8 af[4], bf[4];
            #pragma unroll
            for (int i = 0; i < 4; ++i) {
                const int slot = (((kk >> 3) + quad) ^ (fr & 7)) * 8;
                af[i] = *(const half8*)(&As[(wm + i * 16 + fr) * BK + slot]);
                bf[i] = *(const half8*)(&Bs[(wn + i * 16 + fr) * BK + slot]);
            }
            #pragma unroll
            for (int i = 0; i < 4; ++i)
                #pragma unroll
                for (int j = 0; j < 4; ++j)
                    acc[i][j] = __builtin_amdgcn_mfma_f32_16x16x32_f16(
                        af[i], bf[j], acc[i][j], 0, 0, 0);
        }
        __syncthreads();
    }

    #pragma unroll
    for (int i = 0; i < 4; ++i) {
        #pragma unroll
        for (int j = 0; j < 4; ++j) {
            #pragma unroll
            for (int r = 0; r < 4; ++r) {
                const size_t gm = m0 + wm + i * 16 + quad * 4 + r;
                const size_t gn = n0 + wn + j * 16 + fr;
                float v = acc[i][j][r] + bias[gn];
                if (epi == 1) {
                    float sl = v / (1.f + __expf(-v));
                    out_h[gm * N + gn] = (_Float16)sl;
                } else {
                    out_f[gm * N + gn] = v + resid[gm * N + gn];
                }
            }
        }
    }
}

extern "C" void kernel_launch(void* const* d_in, const int* in_sizes, int n_in,
                              void* d_out, int out_size, void* d_ws, size_t ws_size,
                              hipStream_t stream) {
    const float* x    = (const float*)d_in[0];
    const float* ln1w = (const float*)d_in[1];
    const float* ln1b = (const float*)d_in[2];
    const float* ln2w = (const float*)d_in[3];
    const float* ln2b = (const float*)d_in[4];
    const float* sc   = (const float*)d_in[5];
    const float* pre  = (const float*)d_in[6];
    const float* pim  = (const float*)d_in[7];
    const float* lre  = (const float*)d_in[8];
    const float* lim  = (const float*)d_in[9];
    const float* w1   = (const float*)d_in[10];
    const float* b1   = (const float*)d_in[11];
    const float* w2   = (const float*)d_in[12];
    const float* b2   = (const float*)d_in[13];

    char* ws = (char*)d_ws;
    float2*     e   = (float2*)(ws + E_OFF);
    float2*     sv  = (float2*)(ws + SV_OFF);
    _Float16*   h2  = (_Float16*)(ws + H2_OFF);
    _Float16*   w1h = (_Float16*)(ws + W1H_OFF);
    _Float16*   w2h = (_Float16*)(ws + W2H_OFF);
    _Float16*   y1  = (_Float16*)(ws + Y1_OFF);
    float*      x2  = (float*)d_out;
    float*      outp = (float*)d_out;

    cast2_f32_f16<<<dim3(2 * FFD * DIMD / 1024), 256, 0, stream>>>(w1, w2, w1h, w2h);
    scan_phase1<<<dim3(CHUNKS, BATCH), 256, 0, stream>>>(x, ln1w, ln1b, pre, pim, e);
    scan_combine<<<dim3(DIMD / 256, BATCH), 256, 0, stream>>>(e, pre, pim, lre, lim, sv);
    scan_phase2<<<dim3(CHUNKS, BATCH), 256, 0, stream>>>(
        x, ln1w, ln1b, ln2w, ln2b, pre, pim, sc, sv, x2, h2);
    gemm_bt<<<dim3(FFD / BN, MROWS / BM), 256, 0, stream>>>(
        h2, w1h, b1, y1, nullptr, nullptr, FFD, DIMD, 1);
    gemm_bt<<<dim3(DIMD / BN, MROWS / BM), 256, 0, stream>>>(
        y1, w2h, b2, nullptr, x2, outp, DIMD, FFD, 2);
}

// Round 6
// 384.879 us; speedup vs baseline: 1.0413x; 1.0216x over previous
//
#include <hip/hip_runtime.h>
#include <cmath>

// ---------------------------------------------------------------------------
// SConvNetBlock: LN1 -> SiLU -> complex-decay scan (== reference FFT conv)
//                -> *sc_lin -> +res -> LN2 -> FFN(GEMM+SiLU+GEMM) -> +res
//  * Elementwise chain: CLEN=8 rows per block, rows in registers, batched LN
//    reductions (1-2 barriers per kernel). phase1 -> combine -> phase2.
//  * GEMMs fp16 MFMA 16x16x32, fp32 acc, 128x128 tile, BK=64,
//    global_load_lds w=16 staging, XOR-swizzled LDS (0 bank conflicts).
//  * NEW: XCD-aware superblock swizzle. 1D grid; xcd = g&7 (round-robin
//    dispatch heuristic), each XCD walks its own 8x8-tile superblock
//    (A+B working set = 4 MB = one XCD's L2) -> panel re-fetches hit L2
//    instead of HBM. Perf-only remap (G16-safe).
//  * x2 stored in d_out (fully written before GEMM2 reads it as residual).
// ---------------------------------------------------------------------------

#define DIMD 1024
#define FFD  4096
#define BATCH 4
#define SEQL 2048
#define MROWS (BATCH*SEQL)      // 8192
#define EPSF 1e-5f
#define CHUNKS 256
#define CLEN (SEQL/CHUNKS)      // 8

typedef __attribute__((ext_vector_type(8))) _Float16 half8;
typedef __attribute__((ext_vector_type(4))) _Float16 half4;
typedef __attribute__((ext_vector_type(4))) float    floatx4;

// ---- workspace layout (bytes) ----
#define E_OFF    0u            // e   float2 [4][256][1024]     8 MB
#define SV_OFF   8388608u      // sv  float2 [4][256][1024]     8 MB
#define H2_OFF   16777216u     // h2  fp16 [8192][1024]        16 MB
#define W1H_OFF  33554432u     // w1h fp16 [4096][1024]         8 MB
#define W2H_OFF  41943040u     // w2h fp16 [1024][4096]         8 MB
#define Y1_OFF   50331648u     // y1  fp16 [8192][4096]        64 MB
// total ~114 MB

__device__ __forceinline__ void load_lds16(const _Float16* g, _Float16* l) {
    __builtin_amdgcn_global_load_lds(
        (const __attribute__((address_space(1))) unsigned int*)g,
        (__attribute__((address_space(3))) unsigned int*)l,
        16, 0, 0);
}

__device__ __forceinline__ void wave_reduce2(float& s, float& q) {
    #pragma unroll
    for (int off = 32; off; off >>= 1) {
        s += __shfl_down(s, off, 64);
        q += __shfl_down(q, off, 64);
    }
}

__device__ __forceinline__ void get_p(const float* pre, const float* pim, int d,
                                      float& pr, float& pi) {
    float re = pre[d], im = pim[d];
    float r = sqrtf(re * re + im * im);
    float t = tanhf(r) / fmaxf(r, 1e-30f);
    pr = re * t; pi = im * t;
}

// both weight casts in one kernel
__global__ __launch_bounds__(256)
void cast2_f32_f16(const float* __restrict__ w1, const float* __restrict__ w2,
                   _Float16* __restrict__ o1, _Float16* __restrict__ o2) {
    int i = (blockIdx.x * 256 + threadIdx.x) * 4;
    const float* src = w1;
    _Float16* dst = o1;
    if (i >= FFD * DIMD) { i -= FFD * DIMD; src = w2; dst = o2; }
    float4 v = *(const float4*)(src + i);
    half4 o;
    o.x = (_Float16)v.x; o.y = (_Float16)v.y; o.z = (_Float16)v.z; o.w = (_Float16)v.w;
    *(half4*)(dst + i) = o;
}

// phase1: x -> LN1+SiLU -> local chunk scan (zero init) -> e
__global__ __launch_bounds__(256)
void scan_phase1(const float* __restrict__ x, const float* __restrict__ lw,
                 const float* __restrict__ lb, const float* __restrict__ pre,
                 const float* __restrict__ pim, float2* __restrict__ e) {
    const int tid = threadIdx.x;
    const int d0 = tid * 4;
    const int c = blockIdx.x, bb = blockIdx.y;
    const int lane = tid & 63, wave = tid >> 6;
    __shared__ float2 red[CLEN][4];

    const size_t rowbase = ((size_t)bb * SEQL + (size_t)c * CLEN) * DIMD;
    float4 xv[CLEN];
    #pragma unroll
    for (int j = 0; j < CLEN; ++j)
        xv[j] = *(const float4*)(x + rowbase + (size_t)j * DIMD + d0);

    #pragma unroll
    for (int j = 0; j < CLEN; ++j) {
        float s = (xv[j].x + xv[j].y) + (xv[j].z + xv[j].w);
        float q = (xv[j].x * xv[j].x + xv[j].y * xv[j].y)
                + (xv[j].z * xv[j].z + xv[j].w * xv[j].w);
        wave_reduce2(s, q);
        if (lane == 0) red[j][wave] = make_float2(s, q);
    }
    __syncthreads();

    float pr[4], pi[4], sr[4] = {}, si[4] = {};
    #pragma unroll
    for (int q = 0; q < 4; ++q) get_p(pre, pim, d0 + q, pr[q], pi[q]);
    const float4 wv = *(const float4*)(lw + d0);
    const float4 bv = *(const float4*)(lb + d0);

    #pragma unroll
    for (int j = 0; j < CLEN; ++j) {
        float2 r0 = red[j][0], r1 = red[j][1], r2 = red[j][2], r3 = red[j][3];
        float s = (r0.x + r1.x) + (r2.x + r3.x);
        float q2 = (r0.y + r1.y) + (r2.y + r3.y);
        const float mu = s * (1.f / DIMD);
        const float rs = rsqrtf(q2 * (1.f / DIMD) - mu * mu + EPSF);
        float o[4] = {
            (xv[j].x - mu) * rs * wv.x + bv.x, (xv[j].y - mu) * rs * wv.y + bv.y,
            (xv[j].z - mu) * rs * wv.z + bv.z, (xv[j].w - mu) * rs * wv.w + bv.w };
        #pragma unroll
        for (int q = 0; q < 4; ++q) {
            float hv = o[q] / (1.f + __expf(-o[q]));
            float nr = pr[q] * sr[q] - pi[q] * si[q] + hv;
            float ni = pr[q] * si[q] + pi[q] * sr[q];
            sr[q] = nr; si[q] = ni;
        }
    }
    float2* ep = e + ((size_t)bb * CHUNKS + c) * DIMD + d0;
    #pragma unroll
    for (int q = 0; q < 4; ++q) ep[q] = make_float2(sr[q], si[q]);
}

// sequential combine over chunks: sv[b][c][d] = state entering chunk c
__global__ __launch_bounds__(256)
void scan_combine(const float2* __restrict__ e, const float* __restrict__ pre,
                  const float* __restrict__ pim, const float* __restrict__ lre,
                  const float* __restrict__ lim, float2* __restrict__ sv) {
    const int d = blockIdx.x * 256 + threadIdx.x;
    const int bb = blockIdx.y;
    float pr, pi; get_p(pre, pim, d, pr, pi);
    float qr = pr, qi = pi;                 // p^CLEN, CLEN=8 -> 3 squarings
    #pragma unroll
    for (int s = 0; s < 3; ++s) {
        float nr = qr * qr - qi * qi;
        float ni = 2.f * qr * qi;
        qr = nr; qi = ni;
    }
    float sr = lre[d], si = lim[d];
    #pragma unroll 8
    for (int c = 0; c < CHUNKS; ++c) {
        const size_t idx = ((size_t)bb * CHUNKS + c) * DIMD + d;
        sv[idx] = make_float2(sr, si);
        float2 ec = e[idx];
        float nr = qr * sr - qi * si + ec.x;
        float ni = qr * si + qi * sr + ec.y;
        sr = nr; si = ni;
    }
}

// phase2: x -> LN1+SiLU replay -> scan (true state) -> x2 write (registers
//         kept) -> batched LN2 (one more barrier) -> h2 fp16 write
__global__ __launch_bounds__(256)
void scan_phase2(const float* __restrict__ x, const float* __restrict__ l1w,
                 const float* __restrict__ l1b, const float* __restrict__ l2w,
                 const float* __restrict__ l2b, const float* __restrict__ pre,
                 const float* __restrict__ pim, const float* __restrict__ sc,
                 const float2* __restrict__ sv, float* __restrict__ x2,
                 _Float16* __restrict__ h2) {
    const int tid = threadIdx.x;
    const int d0 = tid * 4;
    const int c = blockIdx.x, bb = blockIdx.y;
    const int lane = tid & 63, wave = tid >> 6;
    __shared__ float2 redA[CLEN][4];
    __shared__ float2 redB[CLEN][4];

    const size_t rowbase = ((size_t)bb * SEQL + (size_t)c * CLEN) * DIMD;
    float4 xv[CLEN];
    #pragma unroll
    for (int j = 0; j < CLEN; ++j)
        xv[j] = *(const float4*)(x + rowbase + (size_t)j * DIMD + d0);

    #pragma unroll
    for (int j = 0; j < CLEN; ++j) {
        float s = (xv[j].x + xv[j].y) + (xv[j].z + xv[j].w);
        float q = (xv[j].x * xv[j].x + xv[j].y * xv[j].y)
                + (xv[j].z * xv[j].z + xv[j].w * xv[j].w);
        wave_reduce2(s, q);
        if (lane == 0) redA[j][wave] = make_float2(s, q);
    }
    __syncthreads();

    float pr[4], pi[4], sr[4], si[4];
    #pragma unroll
    for (int q = 0; q < 4; ++q) {
        get_p(pre, pim, d0 + q, pr[q], pi[q]);
        float2 s0 = sv[((size_t)bb * CHUNKS + c) * DIMD + d0 + q];
        sr[q] = s0.x; si[q] = s0.y;
    }
    const float4 w1v = *(const float4*)(l1w + d0);
    const float4 b1v = *(const float4*)(l1b + d0);
    const float4 scv = *(const float4*)(sc + d0);

    #pragma unroll
    for (int j = 0; j < CLEN; ++j) {
        float2 r0 = redA[j][0], r1 = redA[j][1], r2 = redA[j][2], r3 = redA[j][3];
        float s = (r0.x + r1.x) + (r2.x + r3.x);
        float q2 = (r0.y + r1.y) + (r2.y + r3.y);
        const float mu = s * (1.f / DIMD);
        const float rs = rsqrtf(q2 * (1.f / DIMD) - mu * mu + EPSF);
        float o[4] = {
            (xv[j].x - mu) * rs * w1v.x + b1v.x, (xv[j].y - mu) * rs * w1v.y + b1v.y,
            (xv[j].z - mu) * rs * w1v.z + b1v.z, (xv[j].w - mu) * rs * w1v.w + b1v.w };
        #pragma unroll
        for (int q = 0; q < 4; ++q) {
            float hv = o[q] / (1.f + __expf(-o[q]));
            float nr = pr[q] * sr[q] - pi[q] * si[q] + hv;
            float ni = pr[q] * si[q] + pi[q] * sr[q];
            sr[q] = nr; si[q] = ni;
        }
        xv[j].x += scv.x * sr[0];
        xv[j].y += scv.y * sr[1];
        xv[j].z += scv.z * sr[2];
        xv[j].w += scv.w * sr[3];
        *(float4*)(x2 + rowbase + (size_t)j * DIMD + d0) = xv[j];
    }

    // batched LN2 over the register-resident x2 rows
    #pragma unroll
    for (int j = 0; j < CLEN; ++j) {
        float s = (xv[j].x + xv[j].y) + (xv[j].z + xv[j].w);
        float q = (xv[j].x * xv[j].x + xv[j].y * xv[j].y)
                + (xv[j].z * xv[j].z + xv[j].w * xv[j].w);
        wave_reduce2(s, q);
        if (lane == 0) redB[j][wave] = make_float2(s, q);
    }
    __syncthreads();

    const float4 w2v = *(const float4*)(l2w + d0);
    const float4 b2v = *(const float4*)(l2b + d0);
    #pragma unroll
    for (int j = 0; j < CLEN; ++j) {
        float2 r0 = redB[j][0], r1 = redB[j][1], r2 = redB[j][2], r3 = redB[j][3];
        float s = (r0.x + r1.x) + (r2.x + r3.x);
        float q2 = (r0.y + r1.y) + (r2.y + r3.y);
        const float mu = s * (1.f / DIMD);
        const float rs = rsqrtf(q2 * (1.f / DIMD) - mu * mu + EPSF);
        half4 hh;
        hh.x = (_Float16)((xv[j].x - mu) * rs * w2v.x + b2v.x);
        hh.y = (_Float16)((xv[j].y - mu) * rs * w2v.y + b2v.y);
        hh.z = (_Float16)((xv[j].z - mu) * rs * w2v.z + b2v.z);
        hh.w = (_Float16)((xv[j].w - mu) * rs * w2v.w + b2v.w);
        *(half4*)(h2 + rowbase + (size_t)j * DIMD + d0) = hh;
    }
}

// ---- GEMM: C[M][N] = A[M][K] * W[N][K]^T, fp16 in, fp32 acc ----
#define BM 128
#define BN 128
#define BK 64

__global__ __launch_bounds__(256)
void gemm_bt(const _Float16* __restrict__ A, const _Float16* __restrict__ W,
             const float* __restrict__ bias, _Float16* __restrict__ out_h,
             const float* resid, float* out_f, int N, int K, int epi) {
    __shared__ _Float16 As[BM * BK];
    __shared__ _Float16 Bs[BN * BK];
    const int tid  = threadIdx.x;
    const int lane = tid & 63;
    const int wave = tid >> 6;
    const int wm = (wave >> 1) * 64;
    const int wn = (wave & 1) * 64;

    // XCD-aware superblock swizzle (1D grid).  g&7 ~ XCD id (round-robin
    // dispatch).  Each XCD owns distinct 8x8-tile superblocks; its ~64
    // concurrent blocks share one superblock: A+B working set 4MB = its L2.
    const int nsc = (N / BN) >> 3;          // supercolumns (8 N-tiles each)
    const int g = blockIdx.x;
    const int xcd = g & 7, slot = g >> 3;
    const int sb = slot >> 6, w = slot & 63;
    const int S = sb * 8 + xcd;             // global superblock id
    const int sm = S / nsc, sn = S - sm * nsc;
    const size_t m0 = (size_t)(sm * 8 + (w >> 3)) * BM;
    const size_t n0 = (size_t)(sn * 8 + (w & 7)) * BN;

    const int fr = lane & 15;
    const int quad = lane >> 4;

    // staging: wave handles rows [wave*32, wave*32+32); each issue = 8 rows.
    // LDS slot (row, cc) <- global chunk cc ^ (row&7); row&7 == lane>>3.
    const int srow = wave * 32 + (lane >> 3);
    const int ccp  = ((lane & 7) ^ (lane >> 3)) * 8;   // swizzled global chunk (halfs)
    const _Float16* ag = A + (m0 + srow) * (size_t)K + ccp;
    const _Float16* wg = W + (n0 + srow) * (size_t)K + ccp;
    _Float16* asl = &As[(wave * 32) * BK];
    _Float16* bsl = &Bs[(wave * 32) * BK];

    floatx4 acc[4][4] = {};

    for (int k0 = 0; k0 < K; k0 += BK) {
        #pragma unroll
        for (int t = 0; t < 4; ++t) {
            load_lds16(ag + k0 + (size_t)(t * 8) * K, asl + t * 8 * BK);
            load_lds16(wg + k0 + (size_t)(t * 8) * K, bsl + t * 8 * BK);
        }
        __syncthreads();
        #pragma unroll
        for (int kk = 0; kk < BK; kk += 32) {
            half8 af[4], bf[4];
            #pragma unroll
            for (int i = 0; i < 4; ++i) {
                const int slot2 = (((kk >> 3) + quad) ^ (fr & 7)) * 8;
                af[i] = *(const half8*)(&As[(wm + i * 16 + fr) * BK + slot2]);
                bf[i] = *(const half8*)(&Bs[(wn + i * 16 + fr) * BK + slot2]);
            }
            #pragma unroll
            for (int i = 0; i < 4; ++i)
                #pragma unroll
                for (int j = 0; j < 4; ++j)
                    acc[i][j] = __builtin_amdgcn_mfma_f32_16x16x32_f16(
                        af[i], bf[j], acc[i][j], 0, 0, 0);
        }
        __syncthreads();
    }

    #pragma unroll
    for (int i = 0; i < 4; ++i) {
        #pragma unroll
        for (int j = 0; j < 4; ++j) {
            #pragma unroll
            for (int r = 0; r < 4; ++r) {
                const size_t gm = m0 + wm + i * 16 + quad * 4 + r;
                const size_t gn = n0 + wn + j * 16 + fr;
                float v = acc[i][j][r] + bias[gn];
                if (epi == 1) {
                    float sl = v / (1.f + __expf(-v));
                    out_h[gm * N + gn] = (_Float16)sl;
                } else {
                    out_f[gm * N + gn] = v + resid[gm * N + gn];
                }
            }
        }
    }
}

extern "C" void kernel_launch(void* const* d_in, const int* in_sizes, int n_in,
                              void* d_out, int out_size, void* d_ws, size_t ws_size,
                              hipStream_t stream) {
    const float* x    = (const float*)d_in[0];
    const float* ln1w = (const float*)d_in[1];
    const float* ln1b = (const float*)d_in[2];
    const float* ln2w = (const float*)d_in[3];
    const float* ln2b = (const float*)d_in[4];
    const float* sc   = (const float*)d_in[5];
    const float* pre  = (const float*)d_in[6];
    const float* pim  = (const float*)d_in[7];
    const float* lre  = (const float*)d_in[8];
    const float* lim  = (const float*)d_in[9];
    const float* w1   = (const float*)d_in[10];
    const float* b1   = (const float*)d_in[11];
    const float* w2   = (const float*)d_in[12];
    const float* b2   = (const float*)d_in[13];

    char* ws = (char*)d_ws;
    float2*     e   = (float2*)(ws + E_OFF);
    float2*     sv  = (float2*)(ws + SV_OFF);
    _Float16*   h2  = (_Float16*)(ws + H2_OFF);
    _Float16*   w1h = (_Float16*)(ws + W1H_OFF);
    _Float16*   w2h = (_Float16*)(ws + W2H_OFF);
    _Float16*   y1  = (_Float16*)(ws + Y1_OFF);
    float*      x2  = (float*)d_out;
    float*      outp = (float*)d_out;

    cast2_f32_f16<<<dim3(2 * FFD * DIMD / 1024), 256, 0, stream>>>(w1, w2, w1h, w2h);
    scan_phase1<<<dim3(CHUNKS, BATCH), 256, 0, stream>>>(x, ln1w, ln1b, pre, pim, e);
    scan_combine<<<dim3(DIMD / 256, BATCH), 256, 0, stream>>>(e, pre, pim, lre, lim, sv);
    scan_phase2<<<dim3(CHUNKS, BATCH), 256, 0, stream>>>(
        x, ln1w, ln1b, ln2w, ln2b, pre, pim, sc, sv, x2, h2);
    gemm_bt<<<dim3((MROWS / BM) * (FFD / BN)), 256, 0, stream>>>(
        h2, w1h, b1, y1, nullptr, nullptr, FFD, DIMD, 1);
    gemm_bt<<<dim3((MROWS / BM) * (DIMD / BN)), 256, 0, stream>>>(
        y1, w2h, b2, nullptr, x2, outp, DIMD, FFD, 2);
}